// Round 17
// baseline (58.600 us; speedup 1.0000x reference)
//
#include <hip/hip_runtime.h>
#include <hip/hip_fp16.h>

#define DDIM 128
#define ACC_BLOCKS 2048
#define NWALK (ACC_BLOCKS * 4)     // full-wave walkers
#define RED_BLOCKS 64

typedef unsigned int uint;
typedef unsigned short ushort;
typedef __attribute__((ext_vector_type(8))) short bf16x8;
typedef __attribute__((ext_vector_type(4))) float f32x4;

static __device__ __forceinline__ ushort f2bf(float x) {
    uint u = __float_as_uint(x);
    u += 0x7fffu + ((u >> 16) & 1u);   // RTN-even
    return (ushort)(u >> 16);
}

static __device__ __forceinline__ bf16x8 load_frag8(const float* base) {
    const float4 p = *reinterpret_cast<const float4*>(base);
    const float4 q = *reinterpret_cast<const float4*>(base + 4);
    bf16x8 f;
    f[0] = (short)f2bf(p.x); f[1] = (short)f2bf(p.y);
    f[2] = (short)f2bf(p.z); f[3] = (short)f2bf(p.w);
    f[4] = (short)f2bf(q.x); f[5] = (short)f2bf(q.y);
    f[6] = (short)f2bf(q.z); f[7] = (short)f2bf(q.w);
    return f;
}

// ---------------- Kernel A (fat): precompute_mfma (blocks < PB) + prep (rest) ----------
__global__ __launch_bounds__(256) void fat_prep_precompute(
    const float* __restrict__ impact,
    const float* __restrict__ W,
    const float* __restrict__ Mm,
    __half* __restrict__ WhH,
    __half* __restrict__ MhH,
    const int* __restrict__ segs,
    const int* __restrict__ node_ids,
    const int* __restrict__ neighbor_ids,
    int* __restrict__ items,
    int* __restrict__ wstart,
    int* __restrict__ done,
    int T, int N, int E, int PB, int whoff, int mhoff)
{
    if ((int)blockIdx.x >= PB) {
        // ---------------- prep part ----------------
        const int x = ((int)blockIdx.x - PB) * 256 + (int)threadIdx.x;
        const int K = N + E;
        if (x == 0) *done = 0;

        if (x < E) {
            const int sc = segs[x];
            const int sp = (x == 0) ? -1 : segs[x - 1];
            const int sn = (x + 1 < E) ? segs[x + 1] : N;   // sentinel > any node

            items[x + sc + 1] = (mhoff + neighbor_ids[x] * 256)
                              | ((sn != sc) ? (int)0x80000000 : 0);

            for (int i = sp + 1; i <= sc; ++i)              // boundary nodes
                items[x + i] = (whoff + node_ids[i] * 256)
                             | ((i < sc) ? (int)0x80000000 : 0);

            if (x == E - 1) {
                for (int i = sc + 1; i < N; ++i)            // trailing deg-0 nodes
                    items[E + i] = (whoff + node_ids[i] * 256) | (int)0x80000000;
#pragma unroll
                for (int q = 0; q < 64; ++q) items[K + q] = whoff;  // pad
            }
        } else if (x <= E + NWALK) {
            const int w = x - E;
            int ws;
            if (w == 0) ws = 0;
            else {
                const long long t = (long long)w * E / NWALK;
                if (t >= E) ws = N + E;
                else {
                    const int n = segs[(int)t];
                    int lo = 0, hi = (int)t;
                    while (lo < hi) {
                        const int mid = (lo + hi) >> 1;
                        if (segs[mid] < n) lo = mid + 1; else hi = mid;
                    }
                    ws = lo + n;           // node n's Wh-item position
                }
            }
            wstart[w] = ws;
        }
        return;
    }

    // ---------------- precompute_mfma part ----------------
    const int lane = threadIdx.x & 63;
    const int wv   = threadIdx.x >> 6;       // 0..3 -> d tiles {2wv, 2wv+1}
    const int t0   = (int)blockIdx.x * 32;
    const int r16  = lane & 15;
    const int kg   = lane >> 4;              // 0..3

    bf16x8 A[2][4];
#pragma unroll
    for (int rt = 0; rt < 2; ++rt) {
        int t = t0 + rt * 16 + r16;
        if (t >= T) t = T - 1;               // clamp; writes masked below
        const float* abase = impact + (size_t)t * DDIM + kg * 8;
#pragma unroll
        for (int k0i = 0; k0i < 4; ++k0i)
            A[rt][k0i] = load_frag8(abase + k0i * 32);
    }

#pragma unroll
    for (int dti = 0; dti < 2; ++dti) {
        const int d0 = (wv * 2 + dti) * 16;
#pragma unroll
        for (int m = 0; m < 2; ++m) {
            const float* mat = (m == 0) ? W : Mm;
            __half* out = (m == 0) ? WhH : MhH;
            const float* bbase = mat + (size_t)(d0 + r16) * DDIM + kg * 8;
            f32x4 acc0 = {0.f, 0.f, 0.f, 0.f};
            f32x4 acc1 = {0.f, 0.f, 0.f, 0.f};
#pragma unroll
            for (int k0i = 0; k0i < 4; ++k0i) {
                const bf16x8 b = load_frag8(bbase + k0i * 32);
                acc0 = __builtin_amdgcn_mfma_f32_16x16x32_bf16(A[0][k0i], b, acc0, 0, 0, 0);
                acc1 = __builtin_amdgcn_mfma_f32_16x16x32_bf16(A[1][k0i], b, acc1, 0, 0, 0);
            }
            const int dcol = d0 + r16;
#pragma unroll
            for (int r = 0; r < 4; ++r) {
                const int tr0 = t0 + kg * 4 + r;
                const int tr1 = tr0 + 16;
                if (tr0 < T) out[(size_t)tr0 * DDIM + dcol] = __float2half(acc0[r]);
                if (tr1 < T) out[(size_t)tr1 * DDIM + dcol] = __float2half(acc1[r]);
            }
        }
    }
}

// ---------------- Kernel B: 32-deep double-buffered gather-accumulate ----------------
// One wave per walker. Item words scalar; gathers saddr-form (scalar row base +
// fixed lane*4 VGPR). 32-item superbatches, 2-deep double buffer = up to 64
// loads in flight per wave. launch_bounds(256,4): VGPR cap 128 so the u/v
// buffers (64 VGPR) stay in registers and batches issue back-to-back.
__global__ __launch_bounds__(256, 4) void accumulate_items(
    const char* __restrict__ tab,
    const int* __restrict__ items,
    const int* __restrict__ wstart,
    float* __restrict__ partials)
{
    const int lane = threadIdx.x & 63;
    const int wv   = __builtin_amdgcn_readfirstlane(threadIdx.x >> 6);
    const int w    = blockIdx.x * 4 + wv;

    const uint lb = (uint)lane << 2;     // 4 B per lane (2 fp16)

    const __half2 zero2 = __floats2half2_rn(0.f, 0.f);
    __half2 cc = zero2;
    float a0 = 0.f, a1 = 0.f;

    int k = __builtin_amdgcn_readfirstlane(wstart[w]);
    const int kend = __builtin_amdgcn_readfirstlane(wstart[w + 1]);

#define GATH(IW) (*reinterpret_cast<const __half2*>(tab + (((uint)(IW)) & 0x7fffffffu) + lb))
#define ACC(IW, V) { \
    cc = __hadd2(cc, V); \
    if ((IW) < 0) { \
        const float2 f = __half22float2(cc); \
        a0 += fmaxf(f.x, 0.f); a1 += fmaxf(f.y, 0.f); \
        cc = zero2; \
    } }
#define LOADI32(I, kk) { \
    _Pragma("unroll") \
    for (int q = 0; q < 8; ++q) \
        I[q] = *reinterpret_cast<const int4*>(items + (kk) + 4 * q); }
#define GATHER32(V, I) { \
    _Pragma("unroll") \
    for (int q = 0; q < 8; ++q) { \
        V[4 * q + 0] = GATH(I[q].x); \
        V[4 * q + 1] = GATH(I[q].y); \
        V[4 * q + 2] = GATH(I[q].z); \
        V[4 * q + 3] = GATH(I[q].w); } }
#define ACC32(V, I) { \
    _Pragma("unroll") \
    for (int q = 0; q < 8; ++q) { \
        ACC(I[q].x, V[4 * q + 0]); \
        ACC(I[q].y, V[4 * q + 1]); \
        ACC(I[q].z, V[4 * q + 2]); \
        ACC(I[q].w, V[4 * q + 3]); } }

    // head: align k to 4 (16 B scalar-load alignment); <= 3 items
    while (k < kend && (k & 3)) {
        const int iw = items[k];
        const __half2 v = GATH(iw);
        ACC(iw, v);
        ++k;
    }

    if (k + 64 <= kend) {
        int4 IA[8], IB[8];
        __half2 u[32], v[32];
        LOADI32(IA, k);
        GATHER32(u, IA);
        LOADI32(IB, k + 32);
        k += 64;
        for (;;) {
            // phase 1: issue B's 32 gathers, then drain A
            GATHER32(v, IB);
            ACC32(u, IA);
            if (k + 32 <= kend) { LOADI32(IA, k); k += 32; }
            else { ACC32(v, IB); break; }
            // phase 2: issue A's 32 gathers, then drain B
            GATHER32(u, IA);
            ACC32(v, IB);
            if (k + 32 <= kend) { LOADI32(IB, k); k += 32; }
            else { ACC32(u, IA); break; }
        }
    }
    // mid tail: 32 then 4 at a time
    if (k + 32 <= kend) {
        int4 IC[8];
        __half2 t32[32];
        LOADI32(IC, k);
        GATHER32(t32, IC);
        ACC32(t32, IC);
        k += 32;
    }
    while (k + 4 <= kend) {
        const int4 Ia = *reinterpret_cast<const int4*>(items + k);
        const __half2 v0 = GATH(Ia.x); const __half2 v1 = GATH(Ia.y);
        const __half2 v2 = GATH(Ia.z); const __half2 v3 = GATH(Ia.w);
        ACC(Ia.x, v0); ACC(Ia.y, v1); ACC(Ia.z, v2); ACC(Ia.w, v3);
        k += 4;
    }
    while (k < kend) {
        const int iw = items[k];
        const __half2 v = GATH(iw);
        ACC(iw, v);
        ++k;
    }

    {   // range ends node-aligned -> cc==0; relu(0)=0 safe
        const float2 f = __half22float2(cc);
        a0 += fmaxf(f.x, 0.f);
        a1 += fmaxf(f.y, 0.f);
    }

    __shared__ float red[4][DDIM];
    red[wv][lane * 2 + 0] = a0;
    red[wv][lane * 2 + 1] = a1;
    __syncthreads();
    const int tid = threadIdx.x;
    if (tid < DDIM) {
        partials[(size_t)blockIdx.x * DDIM + tid] =
            red[0][tid] + red[1][tid] + red[2][tid] + red[3][tid];
    }
}

// ---------------- Kernel C: reduce partials + last-block softmax ----------------
__global__ __launch_bounds__(256) void reduce_softmax(
    const float* __restrict__ partials, float* __restrict__ out2,
    float* __restrict__ out, int* __restrict__ done, int nb)
{
    const int tid = threadIdx.x;
    const int d = tid & (DDIM - 1);
    const int h = tid >> 7;                  // 0..1
    {
        const int rows = nb / RED_BLOCKS;    // 32
        const int r0 = blockIdx.x * rows;
        float s = 0.f;
        for (int r = r0 + h; r < r0 + rows; r += 2)
            s += partials[(size_t)r * DDIM + d];
        __shared__ float red[2][DDIM];
        red[h][d] = s;
        __syncthreads();
        if (tid < DDIM)
            out2[(size_t)blockIdx.x * DDIM + tid] = red[0][tid] + red[1][tid];
    }
    __threadfence();
    __shared__ int isLast;
    if (tid == 0) {
        const int v = atomicAdd(done, 1);
        isLast = (v == RED_BLOCKS - 1) ? 1 : 0;
    }
    __syncthreads();
    if (!isLast) return;
    __threadfence();                          // acquire

    float s = 0.f;
    for (int b = h; b < RED_BLOCKS; b += 2)
        s += out2[(size_t)b * DDIM + d];
    __shared__ float r2[2][DDIM];
    r2[h][d] = s;
    __syncthreads();

    __shared__ float vec[DDIM];
    __shared__ float tmp[DDIM];
    if (tid < DDIM) { const float v = r2[0][tid] + r2[1][tid]; vec[tid] = v; tmp[tid] = v; }
    __syncthreads();
    for (int o = 64; o > 0; o >>= 1) {
        if (tid < o) tmp[tid] = fmaxf(tmp[tid], tmp[tid + o]);
        __syncthreads();
    }
    const float mx = tmp[0];
    __syncthreads();
    float ev = 0.f;
    if (tid < DDIM) { ev = expf(vec[tid] - mx); tmp[tid] = ev; }
    __syncthreads();
    for (int o = 64; o > 0; o >>= 1) {
        if (tid < o) tmp[tid] += tmp[tid + o];
        __syncthreads();
    }
    if (tid < DDIM) out[tid] = ev / tmp[0];
}

extern "C" void kernel_launch(void* const* d_in, const int* in_sizes, int n_in,
                              void* d_out, int out_size, void* d_ws, size_t ws_size,
                              hipStream_t stream) {
    const float* impact        = (const float*)d_in[0];
    const float* W             = (const float*)d_in[1];
    const float* Mm            = (const float*)d_in[2];
    const int*   node_ids      = (const int*)d_in[3];
    const int*   neighbor_ids  = (const int*)d_in[4];
    const int*   neighbor_segs = (const int*)d_in[5];

    const int T = in_sizes[0] / DDIM;   // 10000
    const int N = in_sizes[3];          // 50000
    const int E = in_sizes[4];          // 800000
    const int K = N + E;

    char* ws = (char*)d_ws;
    size_t off = 0;
    const int whoff = (int)off;
    __half* WhH = (__half*)(ws + off);  off += (size_t)T * DDIM * sizeof(__half);   // 2.56 MB
    const int mhoff = (int)off;
    __half* MhH = (__half*)(ws + off);  off += (size_t)T * DDIM * sizeof(__half);   // 2.56 MB
    float* partials = (float*)(ws + off); off += (size_t)ACC_BLOCKS * DDIM * sizeof(float);
    float* part2    = (float*)(ws + off); off += (size_t)RED_BLOCKS * DDIM * sizeof(float);
    int*   done     = (int*)(ws + off);   off += 256;
    off = (off + 255) & ~(size_t)255;                      // align for scalar item loads
    int*   items    = (int*)(ws + off);   off += (size_t)(K + 64) * sizeof(int);
    int*   wstart   = (int*)(ws + off);   off += (size_t)(NWALK + 1) * sizeof(int);
    float* outf     = (float*)d_out;

    const int PB    = (T + 31) / 32;                       // precompute blocks (313)
    const int PREPB = (E + NWALK + 1 + 255) / 256;         // prep blocks (incl. wstart)

    fat_prep_precompute<<<PB + PREPB, 256, 0, stream>>>(
        impact, W, Mm, WhH, MhH, neighbor_segs, node_ids, neighbor_ids,
        items, wstart, done, T, N, E, PB, whoff, mhoff);
    accumulate_items<<<ACC_BLOCKS, 256, 0, stream>>>(ws, items, wstart, partials);
    reduce_softmax<<<RED_BLOCKS, 256, 0, stream>>>(partials, part2, outf, done, ACC_BLOCKS);
}